// Round 15
// baseline (322.308 us; speedup 1.0000x reference)
//
#include <hip/hip_runtime.h>
#include <hip/hip_bf16.h>

typedef __hip_bfloat16 bf16;
typedef unsigned short u16;
typedef short short8 __attribute__((ext_vector_type(8)));
typedef float f32x4 __attribute__((ext_vector_type(4)));

static constexpr int B_   = 8;
static constexpr int Lq_  = 10000;
static constexpr int C_   = 256;
static constexpr int NH_  = 8;
static constexpr int NP_  = 4;
static constexpr int HIMG = 100;
static constexpr int WIMG = 100;
static constexpr int LIN  = 10000;   // H*W

__device__ __forceinline__ u16 f2bf(float x) {
    union { bf16 b; u16 u; } cv; cv.b = __float2bfloat16(x); return cv.u;
}
__device__ __forceinline__ float bf2f(u16 u) {
    return __uint_as_float((unsigned)u << 16);
}

__device__ __forceinline__ void gl_lds16(const void* g, void* l) {
    __builtin_amdgcn_global_load_lds(
        (const __attribute__((address_space(1))) void*)g,
        (__attribute__((address_space(3))) void*)l, 16, 0, 0);
}
__device__ __forceinline__ void drain_barrier() {
    asm volatile("s_waitcnt vmcnt(0) lgkmcnt(0)" ::: "memory");
    __builtin_amdgcn_s_barrier();
}

// ---------------------------------------------------------------------------
// gemm256 (R5/R7-proven): C = A[M][K] @ B + bias, 128x256 tile, 8 waves,
// BK=64, 2-phase dbuf. LN variant fuses resid+LayerNorm -> LINEAR bf16.
// ---------------------------------------------------------------------------
template <bool AF32, bool LN>
__global__ __launch_bounds__(512, 2) void gemm256(
    const void* __restrict__ Av, const u16* __restrict__ Bg,
    const float* __restrict__ bias, const float* __restrict__ resid,
    const float* __restrict__ gw, const float* __restrict__ bw,
    u16* __restrict__ Co, int K)
{
    __shared__ __align__(16) u16 At[2][128 * 64];
    __shared__ __align__(16) u16 Bt[2][256 * 64];
    __shared__ float red[2][128][4];

    const int tid  = threadIdx.x;
    const int lane = tid & 63;
    const int w    = tid >> 6;
    const int wm   = w >> 2, wn = w & 3;
    const int m0   = blockIdx.x * 128;

    f32x4 acc[4][4];
#pragma unroll
    for (int i = 0; i < 4; ++i)
#pragma unroll
        for (int j = 0; j < 4; ++j) acc[i][j] = f32x4{0.f, 0.f, 0.f, 0.f};

    auto stageA = [&](int t) {
        const int kt = t << 6;
        if constexpr (AF32) {
            const int row = tid >> 2;
            const int k0  = (tid & 3) << 4;
            const float* s = (const float*)Av + (size_t)(m0 + row) * K + kt + k0;
            float4 v0 = *(const float4*)(s + 0);
            float4 v1 = *(const float4*)(s + 4);
            float4 v2 = *(const float4*)(s + 8);
            float4 v3 = *(const float4*)(s + 12);
            union { short8 s8; u16 u[8]; } ga, gb;
            ga.u[0]=f2bf(v0.x); ga.u[1]=f2bf(v0.y); ga.u[2]=f2bf(v0.z); ga.u[3]=f2bf(v0.w);
            ga.u[4]=f2bf(v1.x); ga.u[5]=f2bf(v1.y); ga.u[6]=f2bf(v1.z); ga.u[7]=f2bf(v1.w);
            gb.u[0]=f2bf(v2.x); gb.u[1]=f2bf(v2.y); gb.u[2]=f2bf(v2.z); gb.u[3]=f2bf(v2.w);
            gb.u[4]=f2bf(v3.x); gb.u[5]=f2bf(v3.y); gb.u[6]=f2bf(v3.z); gb.u[7]=f2bf(v3.w);
            u16* d = &At[t & 1][row * 64];
            *(short8*)&d[(k0)     ^ ((row & 7) << 3)] = ga.s8;
            *(short8*)&d[(k0 + 8) ^ ((row & 7) << 3)] = gb.s8;
        } else {
#pragma unroll
            for (int i = 0; i < 2; ++i) {
                const int rb  = w * 16 + i * 8;
                const int row = rb + (lane >> 3);
                const int gs  = (lane & 7) ^ (row & 7);
                gl_lds16((const u16*)Av + (size_t)(m0 + row) * K + kt + gs * 8,
                         &At[t & 1][rb * 64]);
            }
        }
    };
    auto stageB = [&](int t) {
        const int kt = t << 6;
#pragma unroll
        for (int i = 0; i < 4; ++i) {
            const int rb  = w * 32 + i * 8;
            const int row = rb + (lane >> 3);
            gl_lds16(Bg + (size_t)row * K + kt + (lane & 7) * 8,
                     &Bt[t & 1][rb * 64]);
        }
    };
    auto compute = [&](int t) {
        const u16* a = At[t & 1];
        const u16* b = Bt[t & 1];
#pragma unroll
        for (int ks = 0; ks < 2; ++ks) {
            const int ko = ks * 32 + ((lane >> 4) << 3);
            short8 bfr[4];
#pragma unroll
            for (int n = 0; n < 4; ++n) {
                const int nr = wn * 64 + n * 16 + (lane & 15);
                bfr[n] = *(const short8*)&b[nr * 64 + (ko ^ ((nr & 7) << 3))];
            }
#pragma unroll
            for (int m = 0; m < 4; ++m) {
                const int ar = wm * 64 + m * 16 + (lane & 15);
                const short8 af = *(const short8*)&a[ar * 64 + (ko ^ ((ar & 7) << 3))];
#pragma unroll
                for (int n = 0; n < 4; ++n)
                    acc[m][n] = __builtin_amdgcn_mfma_f32_16x16x32_bf16(
                        af, bfr[n], acc[m][n], 0, 0, 0);
            }
        }
    };

    stageA(0); stageB(0);
    drain_barrier();
    const int nt = K >> 6;
    for (int t = 0; t < nt; ++t) {
        if (t + 1 < nt) { stageA(t + 1); stageB(t + 1); }
        compute(t);
        drain_barrier();
    }

    float bcol[4], gcol[4], becol[4];
#pragma unroll
    for (int n = 0; n < 4; ++n) {
        const int col = wn * 64 + n * 16 + (lane & 15);
        bcol[n] = bias[col];
        if (LN) { gcol[n] = gw[col]; becol[n] = bw[col]; }
    }

    if constexpr (!LN) {
#pragma unroll
        for (int m = 0; m < 4; ++m)
#pragma unroll
            for (int r = 0; r < 4; ++r) {
                const int lr = wm * 64 + m * 16 + (lane >> 4) * 4 + r;
#pragma unroll
                for (int n = 0; n < 4; ++n) {
                    const int col = wn * 64 + n * 16 + (lane & 15);
                    Co[(size_t)(m0 + lr) * 256 + col] = f2bf(acc[m][n][r] + bcol[n]);
                }
            }
    } else {
        float s[4][4], s2[4][4];
#pragma unroll
        for (int m = 0; m < 4; ++m)
#pragma unroll
            for (int r = 0; r < 4; ++r) {
                const int lr = wm * 64 + m * 16 + (lane >> 4) * 4 + r;
                float ps = 0.f, ps2 = 0.f;
#pragma unroll
                for (int n = 0; n < 4; ++n) {
                    const int col = wn * 64 + n * 16 + (lane & 15);
                    float v = acc[m][n][r] + bcol[n]
                            + resid[(size_t)(m0 + lr) * 256 + col];
                    acc[m][n][r] = v;
                    ps += v; ps2 += v * v;
                }
#pragma unroll
                for (int o = 1; o < 16; o <<= 1) {
                    ps  += __shfl_xor(ps,  o);
                    ps2 += __shfl_xor(ps2, o);
                }
                s[m][r] = ps; s2[m][r] = ps2;
            }
        if ((lane & 15) == 0) {
#pragma unroll
            for (int m = 0; m < 4; ++m)
#pragma unroll
                for (int r = 0; r < 4; ++r) {
                    const int lr = wm * 64 + m * 16 + (lane >> 4) * 4 + r;
                    red[0][lr][wn] = s[m][r];
                    red[1][lr][wn] = s2[m][r];
                }
        }
        __syncthreads();
        if (tid < 128) {
            const float ss  = red[0][tid][0] + red[0][tid][1] + red[0][tid][2] + red[0][tid][3];
            const float ss2 = red[1][tid][0] + red[1][tid][1] + red[1][tid][2] + red[1][tid][3];
            const float mean = ss * (1.f / 256.f);
            const float var  = fmaxf(ss2 * (1.f / 256.f) - mean * mean, 0.f);
            red[0][tid][0] = mean;
            red[1][tid][0] = rsqrtf(var + 1e-5f);
        }
        __syncthreads();
#pragma unroll
        for (int m = 0; m < 4; ++m)
#pragma unroll
            for (int r = 0; r < 4; ++r) {
                const int lr = wm * 64 + m * 16 + (lane >> 4) * 4 + r;
                const float mean = red[0][lr][0];
                const float rstd = red[1][lr][0];
#pragma unroll
                for (int n = 0; n < 4; ++n) {
                    const int col = wn * 64 + n * 16 + (lane & 15);
                    const float o = (acc[m][n][r] - mean) * rstd * gcol[n] + becol[n];
                    Co[(size_t)(m0 + lr) * 256 + col] = f2bf(o);   // LINEAR
                }
            }
    }
}

// ---------------------------------------------------------------------------
// ffn_wave — barrier-minimal fused FFN.
// 8 waves x 16-row strips. A strip in REGISTERS (af[8], loaded once).
// Per chunk c (DFF=128): 4 phases {stage 32KB weight half-tile -> 32 MFMA
// -> drain_barrier}. h = acc1 -> bias/relu -> wave-PRIVATE 4KB swizzled
// scratch (lgkmcnt only, no barrier) -> A-frags for G2. LN2 epilogue is
// fully wave-local. 32 barriers/block (vs 104 in R7). LDS 96 KB.
// Weight storage[n][kg] holds logical k-granule (kg ^ (n&7)) so staging is
// a verbatim gl_lds copy and frag reads are ~2-way bank-free.
// ---------------------------------------------------------------------------
__global__ __launch_bounds__(512, 2) void ffn_wave(
    const u16* __restrict__ q1l, const u16* __restrict__ W1L,
    const u16* __restrict__ W2L, const float* __restrict__ b1,
    const float* __restrict__ b2, const float* __restrict__ g2w,
    const float* __restrict__ be2, float* __restrict__ out)
{
    __shared__ __align__(16) u16 R0[16384];      // 32 KB
    __shared__ __align__(16) u16 R1[16384];      // 32 KB
    __shared__ __align__(16) u16 Hsc[8][2048];   // 32 KB (4 KB per wave)

    const int tid  = threadIdx.x;
    const int lane = tid & 63;
    const int w    = tid >> 6;
    const int m0   = blockIdx.x * 128;
    const int strip = w * 16;
    const int l15  = lane & 15;
    const int lq   = lane >> 4;

    // ---- A strip -> registers: af[t] = q1[row=strip+l15][k=t*32+lq*8 ..+8]
    short8 af[8];
    {
        const u16* aG = q1l + (size_t)(m0 + strip + l15) * 256 + lq * 8;
#pragma unroll
        for (int t = 0; t < 8; ++t)
            af[t] = *(const short8*)(aG + t * 32);
    }

    auto stage = [&](const u16* src, u16* dst) {
#pragma unroll
        for (int i = 0; i < 4; ++i)
            gl_lds16(src + (w * 4 + i) * 512 + lane * 8,
                     dst + (w * 4 + i) * 512);
    };

    f32x4 acc2[16];
#pragma unroll
    for (int i = 0; i < 16; ++i) acc2[i] = f32x4{0.f, 0.f, 0.f, 0.f};

    // G1 half: B1 half-tile [128n][16 kg], row=256B. 16 MFMA x 2 t-steps.
    f32x4 acc1[8];
    auto g1half = [&](const u16* Rg, int half) {
#pragma unroll
        for (int tl = 0; tl < 4; ++tl) {
            const int t = half * 4 + tl;
#pragma unroll
            for (int nf = 0; nf < 8; ++nf) {
                const int n = nf * 16 + l15;
                const short8 bfr = *(const short8*)
                    &Rg[n * 128 + (((tl * 4 + lq) ^ (n & 7)) << 3)];
                acc1[nf] = __builtin_amdgcn_mfma_f32_16x16x32_bf16(
                    af[t], bfr, acc1[nf], 0, 0, 0);
            }
        }
    };
    // G2 half: B2 half-tile [256n][8 kg], row=128B; h-frag from Hsc[w].
    auto g2half = [&](const u16* Rg, int hu) {
#pragma unroll
        for (int ul = 0; ul < 2; ++ul) {
            const int u = hu * 2 + ul;
            const short8 hf = *(const short8*)
                &Hsc[w][l15 * 128 + (((u * 4 + lq) ^ (l15 & 7)) << 3)];
#pragma unroll
            for (int nf = 0; nf < 16; ++nf) {
                const int n = nf * 16 + l15;
                const short8 bfr = *(const short8*)
                    &Rg[n * 64 + (((ul * 4 + lq) ^ (n & 7)) << 3)];
                acc2[nf] = __builtin_amdgcn_mfma_f32_16x16x32_bf16(
                    hf, bfr, acc2[nf], 0, 0, 0);
            }
        }
    };

    // ---- prologue: B1(0).h0 -> R0
    stage(W1L, R0);
    drain_barrier();

    for (int c = 0; c < 8; ++c) {
        const u16* w1c = W1L + (size_t)c * 32768;
        const u16* w2c = W2L + (size_t)c * 32768;
#pragma unroll
        for (int i = 0; i < 8; ++i) acc1[i] = f32x4{0.f, 0.f, 0.f, 0.f};

        // phase 1: B1.h1 -> R1 ; G1 half0 (R0)
        stage(w1c + 16384, R1);
        g1half(R0, 0);
        drain_barrier();
        // phase 2: B2.h0 -> R0 ; G1 half1 (R1)
        stage(w2c, R0);
        g1half(R1, 1);
        drain_barrier();

        // phase 3: B2.h1 -> R1 ; transpose h (wave-private) ; G2 half0 (R0)
        stage(w2c + 16384, R1);
        {
            float b1v[8];
#pragma unroll
            for (int nf = 0; nf < 8; ++nf)
                b1v[nf] = b1[c * 128 + nf * 16 + l15];
#pragma unroll
            for (int nf = 0; nf < 8; ++nf) {
                const int col = nf * 16 + l15;
#pragma unroll
                for (int r = 0; r < 4; ++r) {
                    const int row = lq * 4 + r;
                    Hsc[w][row * 128 + (((col >> 3) ^ (row & 7)) << 3) + (col & 7)]
                        = f2bf(fmaxf(acc1[nf][r] + b1v[nf], 0.f));
                }
            }
        }
        g2half(R0, 0);
        drain_barrier();
        // phase 4: next B1.h0 -> R0 ; G2 half1 (R1)
        if (c < 7) stage(w1c + 32768, R0);
        g2half(R1, 1);
        drain_barrier();
    }

    // ---- epilogue: LN2(q1 + acc2 + b2) -> out f32 (fully wave-local)
    float bcol[16], gcol[16], becol[16];
#pragma unroll
    for (int nf = 0; nf < 16; ++nf) {
        const int col = nf * 16 + l15;
        bcol[nf] = b2[col]; gcol[nf] = g2w[col]; becol[nf] = be2[col];
    }
#pragma unroll
    for (int r = 0; r < 4; ++r) {
        const int grow = m0 + strip + lq * 4 + r;
        float ps = 0.f, ps2 = 0.f;
        float v[16];
#pragma unroll
        for (int nf = 0; nf < 16; ++nf) {
            const int col = nf * 16 + l15;
            v[nf] = acc2[nf][r] + bcol[nf]
                  + bf2f(q1l[(size_t)grow * 256 + col]);
            ps += v[nf]; ps2 += v[nf] * v[nf];
        }
#pragma unroll
        for (int o = 1; o < 16; o <<= 1) {
            ps  += __shfl_xor(ps,  o);
            ps2 += __shfl_xor(ps2, o);
        }
        const float mean = ps * (1.f / 256.f);
        const float var  = fmaxf(ps2 * (1.f / 256.f) - mean * mean, 0.f);
        const float rstd = rsqrtf(var + 1e-5f);
#pragma unroll
        for (int nf = 0; nf < 16; ++nf) {
            const int col = nf * 16 + l15;
            out[(size_t)grow * 256 + col] =
                (v[nf] - mean) * rstd * gcol[nf] + becol[nf];
        }
    }
}

// ---------------------------------------------------------------------------
// 4-wave 128x128 MFMA GEMM — oaw projection only (unchanged).
// ---------------------------------------------------------------------------
__global__ __launch_bounds__(256) void gemm_oaw(
    const float* __restrict__ Av, const u16* __restrict__ Bt,
    const float* __restrict__ bias, float* __restrict__ C,
    int M, int K, int Nreal, int ldc)
{
    __shared__ __align__(16) u16 Asl[2][128 * 32];
    __shared__ __align__(16) u16 Bsl[2][128 * 32];

    const int tid  = threadIdx.x;
    const int lane = tid & 63;
    const int w    = tid >> 6;
    const int wr   = (w >> 1) * 64;
    const int wc   = (w & 1) * 64;
    const int m0   = blockIdx.y * 128;
    const int n0   = blockIdx.x * 128;

    const int srow = lane >> 2;
    const int scol = (lane & 3) << 3;
    const u16* bG = Bt + (size_t)(n0 + w * 32 + srow) * K + scol;
    const size_t rstep16 = (size_t)16 * K;

    const int ar  = lane >> 3;
    const int ac  = (lane & 7) << 2;
    const float* aGf = Av + (size_t)(m0 + w * 32 + ar) * K + ac;

    const int aRoff = (wr + (lane & 15)) * 32 + (lane >> 4) * 8;
    const int bRoff = (wc + (lane & 15)) * 32 + (lane >> 4) * 8;

    f32x4 acc[4][4];
#pragma unroll
    for (int i = 0; i < 4; ++i)
#pragma unroll
        for (int j = 0; j < 4; ++j) acc[i][j] = f32x4{0.f, 0.f, 0.f, 0.f};

    float4 a4[4];
    const int nt = K >> 5;

#pragma unroll
    for (int rep = 0; rep < 4; ++rep)
        a4[rep] = *(const float4*)(aGf + (size_t)(rep * 8) * K);
#pragma unroll
    for (int rep = 0; rep < 4; ++rep) {
        ushort4 v{f2bf(a4[rep].x), f2bf(a4[rep].y), f2bf(a4[rep].z), f2bf(a4[rep].w)};
        *(ushort4*)&Asl[0][(w * 32 + rep * 8 + ar) * 32 + ac] = v;
    }
    gl_lds16(bG, &Bsl[0][(w * 32) * 32]);
    gl_lds16(bG + rstep16, &Bsl[0][(w * 32 + 16) * 32]);
    drain_barrier();

    for (int t = 0; t < nt; ++t) {
        const int cur = t & 1, nxt = cur ^ 1;
        const int k0n = (t + 1) << 5;
        const bool has_next = (t + 1 < nt);
        if (has_next) {
#pragma unroll
            for (int rep = 0; rep < 4; ++rep)
                a4[rep] = *(const float4*)(aGf + k0n + (size_t)(rep * 8) * K);
            gl_lds16(bG + k0n, &Bsl[nxt][(w * 32) * 32]);
            gl_lds16(bG + k0n + rstep16, &Bsl[nxt][(w * 32 + 16) * 32]);
        }
        short8 afr[4], bfr[4];
#pragma unroll
        for (int m = 0; m < 4; ++m) afr[m] = *(const short8*)&Asl[cur][aRoff + m * 16 * 32];
#pragma unroll
        for (int n = 0; n < 4; ++n) bfr[n] = *(const short8*)&Bsl[cur][bRoff + n * 16 * 32];
#pragma unroll
        for (int m = 0; m < 4; ++m)
#pragma unroll
            for (int n = 0; n < 4; ++n)
                acc[m][n] = __builtin_amdgcn_mfma_f32_16x16x32_bf16(
                    afr[m], bfr[n], acc[m][n], 0, 0, 0);
        if (has_next) {
#pragma unroll
            for (int rep = 0; rep < 4; ++rep) {
                ushort4 v{f2bf(a4[rep].x), f2bf(a4[rep].y), f2bf(a4[rep].z), f2bf(a4[rep].w)};
                *(ushort4*)&Asl[nxt][(w * 32 + rep * 8 + ar) * 32 + ac] = v;
            }
        }
        drain_barrier();
    }

#pragma unroll
    for (int n = 0; n < 4; ++n) {
        const int gc = n0 + wc + n * 16 + (lane & 15);
        if (gc >= Nreal) continue;
        const float bv = bias[gc];
        const int gr0 = m0 + wr + (lane >> 4) * 4;
#pragma unroll
        for (int m = 0; m < 4; ++m)
#pragma unroll
            for (int r = 0; r < 4; ++r)
                C[(size_t)(gr0 + m * 16 + r) * ldc + gc] = acc[m][n][r] + bv;
    }
}

// ---------------------------------------------------------------------------
// Weight prep.
// Wvs/Wos: gemm256 [n][kd] with kd XOR (n&7)<<3 (64-slice) — unchanged.
// W1L: per (c,half) 16384-elem half-tile [128n][16kg][8]:
//      storage holds logical k = half*128 + (kg^(n&7))*8 + j; src W1[k][c*128+n].
// W2L: per (c,half) 16384-elem half-tile [256n][8kg][8]:
//      k = c*128 + half*64 + (kg^(n&7))*8 + j; src W2[k][n].
// Woa: linear [128][256] + padded bias (gemm_oaw, unchanged).
// ---------------------------------------------------------------------------
__global__ __launch_bounds__(256) void prep_all(
    const float* __restrict__ Wv, const float* __restrict__ Wo,
    const float* __restrict__ W1, const float* __restrict__ W2,
    const float* __restrict__ Woff, const float* __restrict__ Waw,
    const float* __restrict__ boff, const float* __restrict__ baw,
    u16* __restrict__ Wvs, u16* __restrict__ Wos,
    u16* __restrict__ W1L, u16* __restrict__ W2L,
    u16* __restrict__ Woa, float* __restrict__ boa)
{
    const int idx = blockIdx.x * 256 + threadIdx.x;
    if (idx < 65536) {
        const int n = idx >> 8, kd = idx & 255;
        Wvs[idx] = f2bf(Wv[(size_t)(kd ^ ((n & 7) << 3)) * 256 + n]);
    } else if (idx < 131072) {
        const int i = idx - 65536, n = i >> 8, kd = i & 255;
        Wos[i] = f2bf(Wo[(size_t)(kd ^ ((n & 7) << 3)) * 256 + n]);
    } else if (idx < 393216) {
        const int i = idx - 131072;
        const int c2 = i >> 14;                 // (c,half)
        const int n  = (i >> 7) & 127;
        const int kg = (i >> 3) & 15;
        const int j  = i & 7;
        const int c = c2 >> 1, half = c2 & 1;
        const int k = half * 128 + ((kg ^ (n & 7)) << 3) + j;
        W1L[i] = f2bf(W1[(size_t)k * 1024 + c * 128 + n]);
    } else if (idx < 655360) {
        const int i = idx - 393216;
        const int c2 = i >> 14;
        const int n  = (i >> 6) & 255;
        const int kg = (i >> 3) & 7;
        const int j  = i & 7;
        const int c = c2 >> 1, half = c2 & 1;
        const int k = c * 128 + half * 64 + ((kg ^ (n & 7)) << 3) + j;
        W2L[i] = f2bf(W2[(size_t)k * 256 + n]);
    } else if (idx < 688128) {
        const int i = idx - 655360, n = i >> 8, k = i & 255;
        float v = 0.f;
        if (n < 64)      v = Woff[(size_t)k * 64 + n];
        else if (n < 96) v = Waw[(size_t)k * 32 + (n - 64)];
        Woa[i] = f2bf(v);
    } else if (idx < 688256) {
        const int i = idx - 688128;
        boa[i] = (i < 64) ? boff[i] : (i < 96 ? baw[i - 64] : 0.f);
    }
}

// ---------------------------------------------------------------------------
// Bilinear sampling + attention-weight combine (unchanged).
// ---------------------------------------------------------------------------
__global__ __launch_bounds__(256) void sample_attn(
    const u16* __restrict__ val, const float* __restrict__ oaw,
    const float* __restrict__ refp, u16* __restrict__ attn)
{
    const int t   = threadIdx.x;
    const int gid = blockIdx.x * 64 + (t >> 2);
    const int c0  = (t & 3) << 3;
    const int h   = gid & (NH_ - 1);
    const int bq  = gid >> 3;

    const float* row = oaw + (size_t)bq * 96;
    const float rx = refp[(size_t)bq * 2 + 0] * (float)WIMG;
    const float ry = refp[(size_t)bq * 2 + 1] * (float)HIMG;

    const float4 aw4 = *(const float4*)(row + 64 + h * 4);
    const float mx = fmaxf(fmaxf(aw4.x, aw4.y), fmaxf(aw4.z, aw4.w));
    const float e0 = __expf(aw4.x - mx), e1 = __expf(aw4.y - mx);
    const float e2 = __expf(aw4.z - mx), e3 = __expf(aw4.w - mx);
    const float inv = 1.f / (e0 + e1 + e2 + e3);
    const float w4[4] = {e0 * inv, e1 * inv, e2 * inv, e3 * inv};

    const int b = bq / Lq_;
    const u16* vb = val + (size_t)b * LIN * C_ + h * 32 + c0;

    float acc[8] = {};
#pragma unroll
    for (int p = 0; p < NP_; ++p) {
        const float2 off = *(const float2*)(row + (h * 4 + p) * 2);
        const float x = rx + off.x - 0.5f;
        const float y = ry + off.y - 0.5f;
        const float xf = floorf(x), yf = floorf(y);
        const float lx = x - xf, ly = y - yf;
        const int x0 = (int)xf, y0 = (int)yf;
        const float wp = w4[p];
        const float w00 = wp * (1.f - lx) * (1.f - ly);
        const float w10 = wp * lx * (1.f - ly);
        const float w01 = wp * (1.f - lx) * ly;
        const float w11 = wp * lx * ly;

#pragma unroll
        for (int c = 0; c < 4; ++c) {
            const int xi = x0 + (c & 1);
            const int yi = y0 + (c >> 1);
            const float wc = (c == 0) ? w00 : (c == 1) ? w10 : (c == 2) ? w01 : w11;
            const bool v = ((unsigned)xi < (unsigned)WIMG) & ((unsigned)yi < (unsigned)HIMG);
            const int idx = v ? (yi * WIMG + xi) : 0;
            const float w = v ? wc : 0.f;
            const short8 d = *(const short8*)(vb + (size_t)idx * C_);
#pragma unroll
            for (int j = 0; j < 8; ++j)
                acc[j] = fmaf(w, bf2f(((const u16*)&d)[j]), acc[j]);
        }
    }

    union { short8 s; u16 u[8]; } o;
#pragma unroll
    for (int j = 0; j < 8; ++j) o.u[j] = f2bf(acc[j]);
    *(short8*)(attn + (size_t)bq * C_ + h * 32 + c0) = o.s;
}

// ---------------------------------------------------------------------------
extern "C" void kernel_launch(void* const* d_in, const int* in_sizes, int n_in,
                              void* d_out, int out_size, void* d_ws, size_t ws_size,
                              hipStream_t stream)
{
    const float* query = (const float*)d_in[0];
    const float* src   = (const float*)d_in[1];
    const float* refp  = (const float*)d_in[2];
    const float* W_off = (const float*)d_in[5];
    const float* b_off = (const float*)d_in[6];
    const float* W_aw  = (const float*)d_in[7];
    const float* b_aw  = (const float*)d_in[8];
    const float* W_val = (const float*)d_in[9];
    const float* b_val = (const float*)d_in[10];
    const float* W_out = (const float*)d_in[11];
    const float* b_out = (const float*)d_in[12];
    const float* g1    = (const float*)d_in[13];
    const float* be1   = (const float*)d_in[14];
    const float* W1    = (const float*)d_in[15];
    const float* b1    = (const float*)d_in[16];
    const float* W2    = (const float*)d_in[17];
    const float* b2    = (const float*)d_in[18];
    const float* g2    = (const float*)d_in[19];
    const float* be2   = (const float*)d_in[20];
    float* out = (float*)d_out;

    char* ws = (char*)d_ws;
    const int R = B_ * Lq_;  // 80000

    u16*  val  = (u16*)(ws + 0);           // 40.96 MB
    float* oaw = (float*)(ws + 40960000);  // 30.72 MB
    u16*  attn = (u16*)(ws + 71680000);    // 40.96 MB
    u16*  q1l  = (u16*)(ws + 112640000);   // 40.96 MB (LINEAR bf16)
    u16*  Wvs  = (u16*)(ws + 153600000);
    u16*  Wos  = (u16*)(ws + 153600000 + 131072);
    u16*  W1L  = (u16*)(ws + 153600000 + 262144);
    u16*  W2L  = (u16*)(ws + 153600000 + 786432);
    u16*  Woa  = (u16*)(ws + 153600000 + 1310720);
    float* boa = (float*)(ws + 153600000 + 1376256);

    prep_all<<<2689, 256, 0, stream>>>(W_val, W_out, W1, W2, W_off, W_aw,
                                       b_off, b_aw, Wvs, Wos, W1L, W2L,
                                       Woa, boa);

    // value = src @ W_val + b_val  (A f32) -> bf16 linear
    gemm256<true, false><<<625, 512, 0, stream>>>(
        src, Wvs, b_val, nullptr, nullptr, nullptr, val, 256);

    // oaw = query @ [W_off|W_aw] + bias  (N padded 96->128)
    gemm_oaw<<<dim3(1, 625), 256, 0, stream>>>(
        query, Woa, boa, oaw, R, 256, 96, 96);

    // bilinear sampling + softmax combine -> attn bf16 linear
    sample_attn<<<10000, 256, 0, stream>>>(val, oaw, refp, attn);

    // q1 = LN(query + attn @ W_out + b_out) -> q1l bf16 LINEAR
    gemm256<false, true><<<625, 512, 0, stream>>>(
        attn, Wos, b_out, query, g1, be1, q1l, 256);

    // out = LN(q1 + FFN(q1)) -> f32; barrier-minimal wave-strip FFN
    ffn_wave<<<625, 512, 0, stream>>>(q1l, W1L, W2L, b1, b2, g2, be2, out);
}

// Round 16
// 321.904 us; speedup vs baseline: 1.0013x; 1.0013x over previous
//
#include <hip/hip_runtime.h>
#include <hip/hip_bf16.h>

typedef __hip_bfloat16 bf16;
typedef unsigned short u16;
typedef short short8 __attribute__((ext_vector_type(8)));
typedef float f32x4 __attribute__((ext_vector_type(4)));

static constexpr int B_   = 8;
static constexpr int Lq_  = 10000;
static constexpr int C_   = 256;
static constexpr int NH_  = 8;
static constexpr int NP_  = 4;
static constexpr int HIMG = 100;
static constexpr int WIMG = 100;
static constexpr int LIN  = 10000;   // H*W

__device__ __forceinline__ u16 f2bf(float x) {
    union { bf16 b; u16 u; } cv; cv.b = __float2bfloat16(x); return cv.u;
}
__device__ __forceinline__ float bf2f(u16 u) {
    return __uint_as_float((unsigned)u << 16);
}

__device__ __forceinline__ void gl_lds16(const void* g, void* l) {
    __builtin_amdgcn_global_load_lds(
        (const __attribute__((address_space(1))) void*)g,
        (__attribute__((address_space(3))) void*)l, 16, 0, 0);
}
__device__ __forceinline__ void drain_barrier() {
    asm volatile("s_waitcnt vmcnt(0) lgkmcnt(0)" ::: "memory");
    __builtin_amdgcn_s_barrier();
}

// ---------------------------------------------------------------------------
// gemm256 (R5/R7-proven): C = A[M][K] @ B + bias, 128x256 tile, 8 waves,
// BK=64, 2-phase dbuf. LN variant fuses resid+LayerNorm -> LINEAR bf16.
// ---------------------------------------------------------------------------
template <bool AF32, bool LN>
__global__ __launch_bounds__(512, 2) void gemm256(
    const void* __restrict__ Av, const u16* __restrict__ Bg,
    const float* __restrict__ bias, const float* __restrict__ resid,
    const float* __restrict__ gw, const float* __restrict__ bw,
    u16* __restrict__ Co, int K)
{
    __shared__ __align__(16) u16 At[2][128 * 64];
    __shared__ __align__(16) u16 Bt[2][256 * 64];
    __shared__ float red[2][128][4];

    const int tid  = threadIdx.x;
    const int lane = tid & 63;
    const int w    = tid >> 6;
    const int wm   = w >> 2, wn = w & 3;
    const int m0   = blockIdx.x * 128;

    f32x4 acc[4][4];
#pragma unroll
    for (int i = 0; i < 4; ++i)
#pragma unroll
        for (int j = 0; j < 4; ++j) acc[i][j] = f32x4{0.f, 0.f, 0.f, 0.f};

    auto stageA = [&](int t) {
        const int kt = t << 6;
        if constexpr (AF32) {
            const int row = tid >> 2;
            const int k0  = (tid & 3) << 4;
            const float* s = (const float*)Av + (size_t)(m0 + row) * K + kt + k0;
            float4 v0 = *(const float4*)(s + 0);
            float4 v1 = *(const float4*)(s + 4);
            float4 v2 = *(const float4*)(s + 8);
            float4 v3 = *(const float4*)(s + 12);
            union { short8 s8; u16 u[8]; } ga, gb;
            ga.u[0]=f2bf(v0.x); ga.u[1]=f2bf(v0.y); ga.u[2]=f2bf(v0.z); ga.u[3]=f2bf(v0.w);
            ga.u[4]=f2bf(v1.x); ga.u[5]=f2bf(v1.y); ga.u[6]=f2bf(v1.z); ga.u[7]=f2bf(v1.w);
            gb.u[0]=f2bf(v2.x); gb.u[1]=f2bf(v2.y); gb.u[2]=f2bf(v2.z); gb.u[3]=f2bf(v2.w);
            gb.u[4]=f2bf(v3.x); gb.u[5]=f2bf(v3.y); gb.u[6]=f2bf(v3.z); gb.u[7]=f2bf(v3.w);
            u16* d = &At[t & 1][row * 64];
            *(short8*)&d[(k0)     ^ ((row & 7) << 3)] = ga.s8;
            *(short8*)&d[(k0 + 8) ^ ((row & 7) << 3)] = gb.s8;
        } else {
#pragma unroll
            for (int i = 0; i < 2; ++i) {
                const int rb  = w * 16 + i * 8;
                const int row = rb + (lane >> 3);
                const int gs  = (lane & 7) ^ (row & 7);
                gl_lds16((const u16*)Av + (size_t)(m0 + row) * K + kt + gs * 8,
                         &At[t & 1][rb * 64]);
            }
        }
    };
    auto stageB = [&](int t) {
        const int kt = t << 6;
#pragma unroll
        for (int i = 0; i < 4; ++i) {
            const int rb  = w * 32 + i * 8;
            const int row = rb + (lane >> 3);
            gl_lds16(Bg + (size_t)row * K + kt + (lane & 7) * 8,
                     &Bt[t & 1][rb * 64]);
        }
    };
    auto compute = [&](int t) {
        const u16* a = At[t & 1];
        const u16* b = Bt[t & 1];
#pragma unroll
        for (int ks = 0; ks < 2; ++ks) {
            const int ko = ks * 32 + ((lane >> 4) << 3);
            short8 bfr[4];
#pragma unroll
            for (int n = 0; n < 4; ++n) {
                const int nr = wn * 64 + n * 16 + (lane & 15);
                bfr[n] = *(const short8*)&b[nr * 64 + (ko ^ ((nr & 7) << 3))];
            }
#pragma unroll
            for (int m = 0; m < 4; ++m) {
                const int ar = wm * 64 + m * 16 + (lane & 15);
                const short8 af = *(const short8*)&a[ar * 64 + (ko ^ ((ar & 7) << 3))];
#pragma unroll
                for (int n = 0; n < 4; ++n)
                    acc[m][n] = __builtin_amdgcn_mfma_f32_16x16x32_bf16(
                        af, bfr[n], acc[m][n], 0, 0, 0);
            }
        }
    };

    stageA(0); stageB(0);
    drain_barrier();
    const int nt = K >> 6;
    for (int t = 0; t < nt; ++t) {
        if (t + 1 < nt) { stageA(t + 1); stageB(t + 1); }
        compute(t);
        drain_barrier();
    }

    float bcol[4], gcol[4], becol[4];
#pragma unroll
    for (int n = 0; n < 4; ++n) {
        const int col = wn * 64 + n * 16 + (lane & 15);
        bcol[n] = bias[col];
        if (LN) { gcol[n] = gw[col]; becol[n] = bw[col]; }
    }

    if constexpr (!LN) {
#pragma unroll
        for (int m = 0; m < 4; ++m)
#pragma unroll
            for (int r = 0; r < 4; ++r) {
                const int lr = wm * 64 + m * 16 + (lane >> 4) * 4 + r;
#pragma unroll
                for (int n = 0; n < 4; ++n) {
                    const int col = wn * 64 + n * 16 + (lane & 15);
                    Co[(size_t)(m0 + lr) * 256 + col] = f2bf(acc[m][n][r] + bcol[n]);
                }
            }
    } else {
        float s[4][4], s2[4][4];
#pragma unroll
        for (int m = 0; m < 4; ++m)
#pragma unroll
            for (int r = 0; r < 4; ++r) {
                const int lr = wm * 64 + m * 16 + (lane >> 4) * 4 + r;
                float ps = 0.f, ps2 = 0.f;
#pragma unroll
                for (int n = 0; n < 4; ++n) {
                    const int col = wn * 64 + n * 16 + (lane & 15);
                    float v = acc[m][n][r] + bcol[n]
                            + resid[(size_t)(m0 + lr) * 256 + col];
                    acc[m][n][r] = v;
                    ps += v; ps2 += v * v;
                }
#pragma unroll
                for (int o = 1; o < 16; o <<= 1) {
                    ps  += __shfl_xor(ps,  o);
                    ps2 += __shfl_xor(ps2, o);
                }
                s[m][r] = ps; s2[m][r] = ps2;
            }
        if ((lane & 15) == 0) {
#pragma unroll
            for (int m = 0; m < 4; ++m)
#pragma unroll
                for (int r = 0; r < 4; ++r) {
                    const int lr = wm * 64 + m * 16 + (lane >> 4) * 4 + r;
                    red[0][lr][wn] = s[m][r];
                    red[1][lr][wn] = s2[m][r];
                }
        }
        __syncthreads();
        if (tid < 128) {
            const float ss  = red[0][tid][0] + red[0][tid][1] + red[0][tid][2] + red[0][tid][3];
            const float ss2 = red[1][tid][0] + red[1][tid][1] + red[1][tid][2] + red[1][tid][3];
            const float mean = ss * (1.f / 256.f);
            const float var  = fmaxf(ss2 * (1.f / 256.f) - mean * mean, 0.f);
            red[0][tid][0] = mean;
            red[1][tid][0] = rsqrtf(var + 1e-5f);
        }
        __syncthreads();
#pragma unroll
        for (int m = 0; m < 4; ++m)
#pragma unroll
            for (int r = 0; r < 4; ++r) {
                const int lr = wm * 64 + m * 16 + (lane >> 4) * 4 + r;
                const float mean = red[0][lr][0];
                const float rstd = red[1][lr][0];
#pragma unroll
                for (int n = 0; n < 4; ++n) {
                    const int col = wn * 64 + n * 16 + (lane & 15);
                    const float o = (acc[m][n][r] - mean) * rstd * gcol[n] + becol[n];
                    Co[(size_t)(m0 + lr) * 256 + col] = f2bf(o);   // LINEAR
                }
            }
    }
}

// ---------------------------------------------------------------------------
// ffn_wave — barrier-minimal fused FFN.
// 8 waves x 16-row strips. A strip in REGISTERS (af[8], loaded once).
// Per chunk c (DFF=128): 4 phases {stage 32KB weight half-tile -> 32 MFMA
// -> drain_barrier}. h = acc1 -> bias/relu -> wave-PRIVATE 4KB swizzled
// scratch (lgkmcnt only, no barrier) -> A-frags for G2. LN2 epilogue is
// fully wave-local. 32 barriers/block (vs 104 in R7). LDS 96 KB.
// Weight storage[n][kg] holds logical k-granule (kg ^ (n&7)) so staging is
// a verbatim gl_lds copy and frag reads are ~2-way bank-free.
// ---------------------------------------------------------------------------
__global__ __launch_bounds__(512, 2) void ffn_wave(
    const u16* __restrict__ q1l, const u16* __restrict__ W1L,
    const u16* __restrict__ W2L, const float* __restrict__ b1,
    const float* __restrict__ b2, const float* __restrict__ g2w,
    const float* __restrict__ be2, float* __restrict__ out)
{
    __shared__ __align__(16) u16 R0[16384];      // 32 KB
    __shared__ __align__(16) u16 R1[16384];      // 32 KB
    __shared__ __align__(16) u16 Hsc[8][2048];   // 32 KB (4 KB per wave)

    const int tid  = threadIdx.x;
    const int lane = tid & 63;
    const int w    = tid >> 6;
    const int m0   = blockIdx.x * 128;
    const int strip = w * 16;
    const int l15  = lane & 15;
    const int lq   = lane >> 4;

    // ---- A strip -> registers: af[t] = q1[row=strip+l15][k=t*32+lq*8 ..+8]
    short8 af[8];
    {
        const u16* aG = q1l + (size_t)(m0 + strip + l15) * 256 + lq * 8;
#pragma unroll
        for (int t = 0; t < 8; ++t)
            af[t] = *(const short8*)(aG + t * 32);
    }

    auto stage = [&](const u16* src, u16* dst) {
#pragma unroll
        for (int i = 0; i < 4; ++i)
            gl_lds16(src + (w * 4 + i) * 512 + lane * 8,
                     dst + (w * 4 + i) * 512);
    };

    f32x4 acc2[16];
#pragma unroll
    for (int i = 0; i < 16; ++i) acc2[i] = f32x4{0.f, 0.f, 0.f, 0.f};

    // G1 half: B1 half-tile [128n][16 kg], row=256B. 16 MFMA x 2 t-steps.
    f32x4 acc1[8];
    auto g1half = [&](const u16* Rg, int half) {
#pragma unroll
        for (int tl = 0; tl < 4; ++tl) {
            const int t = half * 4 + tl;
#pragma unroll
            for (int nf = 0; nf < 8; ++nf) {
                const int n = nf * 16 + l15;
                const short8 bfr = *(const short8*)
                    &Rg[n * 128 + (((tl * 4 + lq) ^ (n & 7)) << 3)];
                acc1[nf] = __builtin_amdgcn_mfma_f32_16x16x32_bf16(
                    af[t], bfr, acc1[nf], 0, 0, 0);
            }
        }
    };
    // G2 half: B2 half-tile [256n][8 kg], row=128B; h-frag from Hsc[w].
    auto g2half = [&](const u16* Rg, int hu) {
#pragma unroll
        for (int ul = 0; ul < 2; ++ul) {
            const int u = hu * 2 + ul;
            const short8 hf = *(const short8*)
                &Hsc[w][l15 * 128 + (((u * 4 + lq) ^ (l15 & 7)) << 3)];
#pragma unroll
            for (int nf = 0; nf < 16; ++nf) {
                const int n = nf * 16 + l15;
                const short8 bfr = *(const short8*)
                    &Rg[n * 64 + (((ul * 4 + lq) ^ (n & 7)) << 3)];
                acc2[nf] = __builtin_amdgcn_mfma_f32_16x16x32_bf16(
                    hf, bfr, acc2[nf], 0, 0, 0);
            }
        }
    };

    // ---- prologue: B1(0).h0 -> R0
    stage(W1L, R0);
    drain_barrier();

    for (int c = 0; c < 8; ++c) {
        const u16* w1c = W1L + (size_t)c * 32768;
        const u16* w2c = W2L + (size_t)c * 32768;
#pragma unroll
        for (int i = 0; i < 8; ++i) acc1[i] = f32x4{0.f, 0.f, 0.f, 0.f};

        // phase 1: B1.h1 -> R1 ; G1 half0 (R0)
        stage(w1c + 16384, R1);
        g1half(R0, 0);
        drain_barrier();
        // phase 2: B2.h0 -> R0 ; G1 half1 (R1)
        stage(w2c, R0);
        g1half(R1, 1);
        drain_barrier();

        // phase 3: B2.h1 -> R1 ; transpose h (wave-private) ; G2 half0 (R0)
        stage(w2c + 16384, R1);
        {
            float b1v[8];
#pragma unroll
            for (int nf = 0; nf < 8; ++nf)
                b1v[nf] = b1[c * 128 + nf * 16 + l15];
#pragma unroll
            for (int nf = 0; nf < 8; ++nf) {
                const int col = nf * 16 + l15;
#pragma unroll
                for (int r = 0; r < 4; ++r) {
                    const int row = lq * 4 + r;
                    Hsc[w][row * 128 + (((col >> 3) ^ (row & 7)) << 3) + (col & 7)]
                        = f2bf(fmaxf(acc1[nf][r] + b1v[nf], 0.f));
                }
            }
        }
        g2half(R0, 0);
        drain_barrier();
        // phase 4: next B1.h0 -> R0 ; G2 half1 (R1)
        if (c < 7) stage(w1c + 32768, R0);
        g2half(R1, 1);
        drain_barrier();
    }

    // ---- epilogue: LN2(q1 + acc2 + b2) -> out f32 (fully wave-local)
    float bcol[16], gcol[16], becol[16];
#pragma unroll
    for (int nf = 0; nf < 16; ++nf) {
        const int col = nf * 16 + l15;
        bcol[nf] = b2[col]; gcol[nf] = g2w[col]; becol[nf] = be2[col];
    }
#pragma unroll
    for (int r = 0; r < 4; ++r) {
        const int grow = m0 + strip + lq * 4 + r;
        float ps = 0.f, ps2 = 0.f;
        float v[16];
#pragma unroll
        for (int nf = 0; nf < 16; ++nf) {
            const int col = nf * 16 + l15;
            v[nf] = acc2[nf][r] + bcol[nf]
                  + bf2f(q1l[(size_t)grow * 256 + col]);
            ps += v[nf]; ps2 += v[nf] * v[nf];
        }
#pragma unroll
        for (int o = 1; o < 16; o <<= 1) {
            ps  += __shfl_xor(ps,  o);
            ps2 += __shfl_xor(ps2, o);
        }
        const float mean = ps * (1.f / 256.f);
        const float var  = fmaxf(ps2 * (1.f / 256.f) - mean * mean, 0.f);
        const float rstd = rsqrtf(var + 1e-5f);
#pragma unroll
        for (int nf = 0; nf < 16; ++nf) {
            const int col = nf * 16 + l15;
            out[(size_t)grow * 256 + col] =
                (v[nf] - mean) * rstd * gcol[nf] + becol[nf];
        }
    }
}

// ---------------------------------------------------------------------------
// 4-wave 128x128 MFMA GEMM — oaw projection only (unchanged).
// ---------------------------------------------------------------------------
__global__ __launch_bounds__(256) void gemm_oaw(
    const float* __restrict__ Av, const u16* __restrict__ Bt,
    const float* __restrict__ bias, float* __restrict__ C,
    int M, int K, int Nreal, int ldc)
{
    __shared__ __align__(16) u16 Asl[2][128 * 32];
    __shared__ __align__(16) u16 Bsl[2][128 * 32];

    const int tid  = threadIdx.x;
    const int lane = tid & 63;
    const int w    = tid >> 6;
    const int wr   = (w >> 1) * 64;
    const int wc   = (w & 1) * 64;
    const int m0   = blockIdx.y * 128;
    const int n0   = blockIdx.x * 128;

    const int srow = lane >> 2;
    const int scol = (lane & 3) << 3;
    const u16* bG = Bt + (size_t)(n0 + w * 32 + srow) * K + scol;
    const size_t rstep16 = (size_t)16 * K;

    const int ar  = lane >> 3;
    const int ac  = (lane & 7) << 2;
    const float* aGf = Av + (size_t)(m0 + w * 32 + ar) * K + ac;

    const int aRoff = (wr + (lane & 15)) * 32 + (lane >> 4) * 8;
    const int bRoff = (wc + (lane & 15)) * 32 + (lane >> 4) * 8;

    f32x4 acc[4][4];
#pragma unroll
    for (int i = 0; i < 4; ++i)
#pragma unroll
        for (int j = 0; j < 4; ++j) acc[i][j] = f32x4{0.f, 0.f, 0.f, 0.f};

    float4 a4[4];
    const int nt = K >> 5;

#pragma unroll
    for (int rep = 0; rep < 4; ++rep)
        a4[rep] = *(const float4*)(aGf + (size_t)(rep * 8) * K);
#pragma unroll
    for (int rep = 0; rep < 4; ++rep) {
        ushort4 v{f2bf(a4[rep].x), f2bf(a4[rep].y), f2bf(a4[rep].z), f2bf(a4[rep].w)};
        *(ushort4*)&Asl[0][(w * 32 + rep * 8 + ar) * 32 + ac] = v;
    }
    gl_lds16(bG, &Bsl[0][(w * 32) * 32]);
    gl_lds16(bG + rstep16, &Bsl[0][(w * 32 + 16) * 32]);
    drain_barrier();

    for (int t = 0; t < nt; ++t) {
        const int cur = t & 1, nxt = cur ^ 1;
        const int k0n = (t + 1) << 5;
        const bool has_next = (t + 1 < nt);
        if (has_next) {
#pragma unroll
            for (int rep = 0; rep < 4; ++rep)
                a4[rep] = *(const float4*)(aGf + k0n + (size_t)(rep * 8) * K);
            gl_lds16(bG + k0n, &Bsl[nxt][(w * 32) * 32]);
            gl_lds16(bG + k0n + rstep16, &Bsl[nxt][(w * 32 + 16) * 32]);
        }
        short8 afr[4], bfr[4];
#pragma unroll
        for (int m = 0; m < 4; ++m) afr[m] = *(const short8*)&Asl[cur][aRoff + m * 16 * 32];
#pragma unroll
        for (int n = 0; n < 4; ++n) bfr[n] = *(const short8*)&Bsl[cur][bRoff + n * 16 * 32];
#pragma unroll
        for (int m = 0; m < 4; ++m)
#pragma unroll
            for (int n = 0; n < 4; ++n)
                acc[m][n] = __builtin_amdgcn_mfma_f32_16x16x32_bf16(
                    afr[m], bfr[n], acc[m][n], 0, 0, 0);
        if (has_next) {
#pragma unroll
            for (int rep = 0; rep < 4; ++rep) {
                ushort4 v{f2bf(a4[rep].x), f2bf(a4[rep].y), f2bf(a4[rep].z), f2bf(a4[rep].w)};
                *(ushort4*)&Asl[nxt][(w * 32 + rep * 8 + ar) * 32 + ac] = v;
            }
        }
        drain_barrier();
    }

#pragma unroll
    for (int n = 0; n < 4; ++n) {
        const int gc = n0 + wc + n * 16 + (lane & 15);
        if (gc >= Nreal) continue;
        const float bv = bias[gc];
        const int gr0 = m0 + wr + (lane >> 4) * 4;
#pragma unroll
        for (int m = 0; m < 4; ++m)
#pragma unroll
            for (int r = 0; r < 4; ++r)
                C[(size_t)(gr0 + m * 16 + r) * ldc + gc] = acc[m][n][r] + bv;
    }
}

// ---------------------------------------------------------------------------
// Weight prep.
// Wvs/Wos: gemm256 [n][kd] with kd XOR (n&7)<<3 (64-slice) — unchanged.
// W1L: per (c,half) 16384-elem half-tile [128n][16kg][8]:
//      storage holds logical k = half*128 + (kg^(n&7))*8 + j; src W1[k][c*128+n].
// W2L: per (c,half) 16384-elem half-tile [256n][8kg][8]:
//      k = c*128 + half*64 + (kg^(n&7))*8 + j; src W2[k][n].
// Woa: linear [128][256] + padded bias (gemm_oaw, unchanged).
// ---------------------------------------------------------------------------
__global__ __launch_bounds__(256) void prep_all(
    const float* __restrict__ Wv, const float* __restrict__ Wo,
    const float* __restrict__ W1, const float* __restrict__ W2,
    const float* __restrict__ Woff, const float* __restrict__ Waw,
    const float* __restrict__ boff, const float* __restrict__ baw,
    u16* __restrict__ Wvs, u16* __restrict__ Wos,
    u16* __restrict__ W1L, u16* __restrict__ W2L,
    u16* __restrict__ Woa, float* __restrict__ boa)
{
    const int idx = blockIdx.x * 256 + threadIdx.x;
    if (idx < 65536) {
        const int n = idx >> 8, kd = idx & 255;
        Wvs[idx] = f2bf(Wv[(size_t)(kd ^ ((n & 7) << 3)) * 256 + n]);
    } else if (idx < 131072) {
        const int i = idx - 65536, n = i >> 8, kd = i & 255;
        Wos[i] = f2bf(Wo[(size_t)(kd ^ ((n & 7) << 3)) * 256 + n]);
    } else if (idx < 393216) {
        const int i = idx - 131072;
        const int c2 = i >> 14;                 // (c,half)
        const int n  = (i >> 7) & 127;
        const int kg = (i >> 3) & 15;
        const int j  = i & 7;
        const int c = c2 >> 1, half = c2 & 1;
        const int k = half * 128 + ((kg ^ (n & 7)) << 3) + j;
        W1L[i] = f2bf(W1[(size_t)k * 1024 + c * 128 + n]);
    } else if (idx < 655360) {
        const int i = idx - 393216;
        const int c2 = i >> 14;
        const int n  = (i >> 6) & 255;
        const int kg = (i >> 3) & 7;
        const int j  = i & 7;
        const int c = c2 >> 1, half = c2 & 1;
        const int k = c * 128 + half * 64 + ((kg ^ (n & 7)) << 3) + j;
        W2L[i] = f2bf(W2[(size_t)k * 256 + n]);
    } else if (idx < 688128) {
        const int i = idx - 655360, n = i >> 8, k = i & 255;
        float v = 0.f;
        if (n < 64)      v = Woff[(size_t)k * 64 + n];
        else if (n < 96) v = Waw[(size_t)k * 32 + (n - 64)];
        Woa[i] = f2bf(v);
    } else if (idx < 688256) {
        const int i = idx - 688128;
        boa[i] = (i < 64) ? boff[i] : (i < 96 ? baw[i - 64] : 0.f);
    }
}

// ---------------------------------------------------------------------------
// Bilinear sampling + attention-weight combine (unchanged).
// ---------------------------------------------------------------------------
__global__ __launch_bounds__(256) void sample_attn(
    const u16* __restrict__ val, const float* __restrict__ oaw,
    const float* __restrict__ refp, u16* __restrict__ attn)
{
    const int t   = threadIdx.x;
    const int gid = blockIdx.x * 64 + (t >> 2);
    const int c0  = (t & 3) << 3;
    const int h   = gid & (NH_ - 1);
    const int bq  = gid >> 3;

    const float* row = oaw + (size_t)bq * 96;
    const float rx = refp[(size_t)bq * 2 + 0] * (float)WIMG;
    const float ry = refp[(size_t)bq * 2 + 1] * (float)HIMG;

    const float4 aw4 = *(const float4*)(row + 64 + h * 4);
    const float mx = fmaxf(fmaxf(aw4.x, aw4.y), fmaxf(aw4.z, aw4.w));
    const float e0 = __expf(aw4.x - mx), e1 = __expf(aw4.y - mx);
    const float e2 = __expf(aw4.z - mx), e3 = __expf(aw4.w - mx);
    const float inv = 1.f / (e0 + e1 + e2 + e3);
    const float w4[4] = {e0 * inv, e1 * inv, e2 * inv, e3 * inv};

    const int b = bq / Lq_;
    const u16* vb = val + (size_t)b * LIN * C_ + h * 32 + c0;

    float acc[8] = {};
#pragma unroll
    for (int p = 0; p < NP_; ++p) {
        const float2 off = *(const float2*)(row + (h * 4 + p) * 2);
        const float x = rx + off.x - 0.5f;
        const float y = ry + off.y - 0.5f;
        const float xf = floorf(x), yf = floorf(y);
        const float lx = x - xf, ly = y - yf;
        const int x0 = (int)xf, y0 = (int)yf;
        const float wp = w4[p];
        const float w00 = wp * (1.f - lx) * (1.f - ly);
        const float w10 = wp * lx * (1.f - ly);
        const float w01 = wp * (1.f - lx) * ly;
        const float w11 = wp * lx * ly;

#pragma unroll
        for (int c = 0; c < 4; ++c) {
            const int xi = x0 + (c & 1);
            const int yi = y0 + (c >> 1);
            const float wc = (c == 0) ? w00 : (c == 1) ? w10 : (c == 2) ? w01 : w11;
            const bool v = ((unsigned)xi < (unsigned)WIMG) & ((unsigned)yi < (unsigned)HIMG);
            const int idx = v ? (yi * WIMG + xi) : 0;
            const float w = v ? wc : 0.f;
            const short8 d = *(const short8*)(vb + (size_t)idx * C_);
#pragma unroll
            for (int j = 0; j < 8; ++j)
                acc[j] = fmaf(w, bf2f(((const u16*)&d)[j]), acc[j]);
        }
    }

    union { short8 s; u16 u[8]; } o;
#pragma unroll
    for (int j = 0; j < 8; ++j) o.u[j] = f2bf(acc[j]);
    *(short8*)(attn + (size_t)bq * C_ + h * 32 + c0) = o.s;
}

// ---------------------------------------------------------------------------
extern "C" void kernel_launch(void* const* d_in, const int* in_sizes, int n_in,
                              void* d_out, int out_size, void* d_ws, size_t ws_size,
                              hipStream_t stream)
{
    const float* query = (const float*)d_in[0];
    const float* src   = (const float*)d_in[1];
    const float* refp  = (const float*)d_in[2];
    const float* W_off = (const float*)d_in[5];
    const float* b_off = (const float*)d_in[6];
    const float* W_aw  = (const float*)d_in[7];
    const float* b_aw  = (const float*)d_in[8];
    const float* W_val = (const float*)d_in[9];
    const float* b_val = (const float*)d_in[10];
    const float* W_out = (const float*)d_in[11];
    const float* b_out = (const float*)d_in[12];
    const float* g1    = (const float*)d_in[13];
    const float* be1   = (const float*)d_in[14];
    const float* W1    = (const float*)d_in[15];
    const float* b1    = (const float*)d_in[16];
    const float* W2    = (const float*)d_in[17];
    const float* b2    = (const float*)d_in[18];
    const float* g2    = (const float*)d_in[19];
    const float* be2   = (const float*)d_in[20];
    float* out = (float*)d_out;

    char* ws = (char*)d_ws;
    const int R = B_ * Lq_;  // 80000

    u16*  val  = (u16*)(ws + 0);           // 40.96 MB
    float* oaw = (float*)(ws + 40960000);  // 30.72 MB
    u16*  attn = (u16*)(ws + 71680000);    // 40.96 MB
    u16*  q1l  = (u16*)(ws + 112640000);   // 40.96 MB (LINEAR bf16)
    u16*  Wvs  = (u16*)(ws + 153600000);
    u16*  Wos  = (u16*)(ws + 153600000 + 131072);
    u16*  W1L  = (u16*)(ws + 153600000 + 262144);
    u16*  W2L  = (u16*)(ws + 153600000 + 786432);
    u16*  Woa  = (u16*)(ws + 153600000 + 1310720);
    float* boa = (float*)(ws + 153600000 + 1376256);

    prep_all<<<2689, 256, 0, stream>>>(W_val, W_out, W1, W2, W_off, W_aw,
                                       b_off, b_aw, Wvs, Wos, W1L, W2L,
                                       Woa, boa);

    // value = src @ W_val + b_val  (A f32) -> bf16 linear
    gemm256<true, false><<<625, 512, 0, stream>>>(
        src, Wvs, b_val, nullptr, nullptr, nullptr, val, 256);

    // oaw = query @ [W_off|W_aw] + bias  (N padded 96->128)
    gemm_oaw<<<dim3(1, 625), 256, 0, stream>>>(
        query, Woa, boa, oaw, R, 256, 96, 96);

    // bilinear sampling + softmax combine -> attn bf16 linear
    sample_attn<<<10000, 256, 0, stream>>>(val, oaw, refp, attn);

    // q1 = LN(query + attn @ W_out + b_out) -> q1l bf16 LINEAR
    gemm256<false, true><<<625, 512, 0, stream>>>(
        attn, Wos, b_out, query, g1, be1, q1l, 256);

    // out = LN(q1 + FFN(q1)) -> f32; barrier-minimal wave-strip FFN
    ffn_wave<<<625, 512, 0, stream>>>(q1l, W1L, W2L, b1, b2, g2, be2, out);
}